// Round 1
// baseline (601.669 us; speedup 1.0000x reference)
//
#include <hip/hip_runtime.h>

typedef float f2 __attribute__((ext_vector_type(2)));

#define PAD 5
#define WSZ 11

// Precomputed normalized 11-tap Gaussian (sigma=1.5) — matches fp32 ref far
// within the 1.4e-2 threshold. Hard-coded to keep weights out of VGPRs.
__device__ __forceinline__ float gw(int k) {
    const float G[WSZ] = {
        0.0010283782f, 0.0075987580f, 0.0360007600f, 0.1093607000f,
        0.2130055600f, 0.2660117400f,
        0.2130055600f, 0.1093607000f, 0.0360007600f, 0.0075987580f, 0.0010283782f };
    return G[k];
}

__global__ __launch_bounds__(64) void init_accum_kernel(double* accum) {
    if (threadIdx.x < 4) accum[threadIdx.x] = 0.0;
}

// 4 independent waves per 256-thread block; each wave owns a 64-col x RT-row
// strip and a private 80-entry LDS row (no cross-wave sharing -> no barriers;
// same-wave DS ordering + wavefront fences keep prefetch loads in flight).
// Depth-2 global prefetch into register slots P0/P1 (slot = it&1, static after
// unroll-by-12). Horizontal 11-tap via the 74-wide LDS row; vertical 11-tap
// via a 12-deep register ring (static indices). 2x2 pool fused.
template<int RT, bool PLANAR>
__global__ __launch_bounds__(256, 6) void ssim_scale_kernel(
    const float* __restrict__ img1, const float* __restrict__ img2,
    const f2* __restrict__ pair,
    int H, int W,
    double* __restrict__ accum, int slot,
    f2* __restrict__ pout)
{
    __shared__ f2 st_all[4][80];          // per-wave strip: cols ox-5 .. ox+68
    const int lane = threadIdx.x & 63;
    const int wv   = threadIdx.x >> 6;
    f2* st = st_all[wv];
    const int ox = blockIdx.x * 64;
    const int r0 = (blockIdx.y * 4 + wv) * RT;
    const int z  = blockIdx.z;
    const size_t base = (size_t)z * H * W;

    constexpr int NIT = RT + 10;
    const float C1 = 1e-4f, C2 = 9e-4f;

    // Per-lane column geometry (iteration-invariant).
    const int c0 = ox - PAD + lane;
    const bool m0 = (c0 >= 0) & (c0 < W);
    const int c0c = min(max(c0, 0), W - 1);
    const int c1 = ox + 59 + lane;                 // halo cols, lanes 0..9
    const bool m1 = (lane < 10) & (c1 < W);
    const int c1c = min(c1, W - 1);

    f2 P0a = {0.f, 0.f}, P0b = {0.f, 0.f};
    f2 P1a = {0.f, 0.f}, P1b = {0.f, 0.f};

    auto issue = [&](int y, f2& A, f2& B) {
        int yc = min(max(y, 0), H - 1);            // clamp; mask at consume
        const size_t roff = base + (size_t)yc * W; // wave-uniform -> SALU
        if (PLANAR) {
            A = (f2){ img1[roff + c0c], img2[roff + c0c] };
            if (lane < 10) B = (f2){ img1[roff + c1c], img2[roff + c1c] };
        } else {
            A = pair[roff + c0c];
            if (lane < 10) B = pair[roff + c1c];
        }
    };

    issue(r0 - PAD + 0, P0a, P0b);
    issue(r0 - PAD + 1, P1a, P1b);

    f2 rmu[12], rsq[12];
    float rxx[12];
    f2 psum = {0.f, 0.f};
    float local = 0.f;
    const f2 zero = {0.f, 0.f};

#pragma clang loop unroll(disable)
    for (int b0 = 0; b0 < NIT; b0 += 12) {
#pragma unroll
        for (int j = 0; j < 12; ++j) {
            const int it = b0 + j;
            if (it < NIT) {
                const int y = r0 - PAD + it;
                const bool yok = (y >= 0) & (y < H);   // wave-uniform

                f2& ca = (j & 1) ? P1a : P0a;          // static slot select
                f2& cb = (j & 1) ? P1b : P0b;
                f2 wa = (yok & m0) ? ca : zero;        // vmcnt wait lands here
                f2 wb = (yok & m1) ? cb : zero;
                issue(y + 2, ca, cb);                  // refill slot: depth-2 prefetch

                __builtin_amdgcn_fence(__ATOMIC_ACQ_REL, "wavefront");
                __builtin_amdgcn_wave_barrier();
                st[lane] = wa;
                if (lane < 10) st[64 + lane] = wb;
                __builtin_amdgcn_fence(__ATOMIC_ACQ_REL, "wavefront");
                __builtin_amdgcn_wave_barrier();

                // Horizontal 11-tap (same-wave DS ordering guarantees RAW).
                f2 hmu = zero, hsq = zero;
                float hxx = 0.f;
#pragma unroll
                for (int k = 0; k < WSZ; ++k) {
                    f2 p = st[lane + k];
                    hmu += p * gw(k);
                    hsq += (p * p) * gw(k);
                    hxx += (p.x * p.y) * gw(k);
                }
                rmu[it % 12] = hmu;                    // it%12 == j: static
                rsq[it % 12] = hsq;
                rxx[it % 12] = hxx;

                // Fused 2x2 avg-pool from the staged raw row.
                if (pout != nullptr) {
                    const int yt = it - PAD;
                    if ((yt >= 0) & (yt < RT) & (lane < 32)) {
                        f2 s01 = st[PAD + 2 * lane] + st[PAD + 2 * lane + 1];
                        if ((yt & 1) == 0) {
                            psum = s01;
                        } else {
                            f2 m = (psum + s01) * 0.25f;
                            const int Wo = W >> 1;
                            pout[(size_t)z * (H >> 1) * Wo +
                                 (size_t)((r0 + yt) >> 1) * Wo + (ox >> 1) + lane] = m;
                        }
                    }
                }

                // Vertical 11-tap + SSIM.
                if (it >= 10) {
                    f2 vmu = zero, vsq = zero;
                    float vxx = 0.f;
#pragma unroll
                    for (int k = 0; k < WSZ; ++k) {
                        const int s = (j + 2 + k) % 12;  // static after unroll
                        vmu += rmu[s] * gw(k);
                        vsq += rsq[s] * gw(k);
                        vxx += rxx[s] * gw(k);
                    }
                    const float mu1 = vmu.x, mu2 = vmu.y;
                    const float mu11 = mu1 * mu1, mu22 = mu2 * mu2, mu12 = mu1 * mu2;
                    const float sig1 = vsq.x - mu11;
                    const float sig2 = vsq.y - mu22;
                    const float sig12 = vxx - mu12;
                    const float num = (2.f * mu12 + C1) * (2.f * sig12 + C2);
                    const float den = (mu11 + mu22 + C1) * (sig1 + sig2 + C2);
                    local += num * __builtin_amdgcn_rcpf(den);
                }
            }
        }
    }

#pragma unroll
    for (int off = 32; off > 0; off >>= 1) local += __shfl_down(local, off);
    if (lane == 0) atomicAdd(&accum[slot], (double)local);
}

__global__ void finalize_kernel(const double* __restrict__ accum, float* __restrict__ out,
                                double c0, double c1, double c2, double c3)
{
    const double w[4] = {0.0448, 0.2856, 0.3001, 0.2363};
    const double cnt[4] = {c0, c1, c2, c3};
    double loss = 0.0;
#pragma unroll
    for (int s = 0; s < 4; ++s) loss += w[s] * (1.0 - accum[s] / cnt[s]);
    out[0] = (float)loss;
}

extern "C" void kernel_launch(void* const* d_in, const int* in_sizes, int n_in,
                              void* d_out, int out_size, void* d_ws, size_t ws_size,
                              hipStream_t stream) {
    const float* img1 = (const float*)d_in[0];
    const float* img2 = (const float*)d_in[1];
    float* out = (float*)d_out;

    const int H0 = 512, W0 = 512;
    const int NC = in_sizes[0] / (H0 * W0);  // 48

    double* accum = (double*)d_ws;
    f2* p1 = (f2*)((char*)d_ws + 64);                 // NC*256*256
    f2* p2 = p1 + (size_t)NC * 256 * 256;             // NC*128*128
    f2* p3 = p2 + (size_t)NC * 128 * 128;             // NC*64*64

    init_accum_kernel<<<1, 64, 0, stream>>>(accum);

    // Scale 0: RT=32, 16 strips, 4 waves/block -> 8x4x48 blocks = 6144 waves
    //          (24 waves/CU nominal vs 12 before; halo VALU +13.5%)
    ssim_scale_kernel<32, true><<<dim3(8, 4, NC), 256, 0, stream>>>(
        img1, img2, nullptr, 512, 512, accum, 0, p1);
    // Scale 1: RT=8, 32 strips -> 4x8x48 blocks = 6144 waves (was 3072)
    ssim_scale_kernel<8, false><<<dim3(4, 8, NC), 256, 0, stream>>>(
        nullptr, nullptr, p1, 256, 256, accum, 1, p2);
    // Scale 2: RT=8, 16 strips -> 2x4x48 blocks = 1536 waves
    ssim_scale_kernel<8, false><<<dim3(2, 4, NC), 256, 0, stream>>>(
        nullptr, nullptr, p2, 128, 128, accum, 2, p3);
    // Scale 3: RT=8, 8 strips -> 1x2x48 blocks = 384 waves
    ssim_scale_kernel<8, false><<<dim3(1, 2, NC), 256, 0, stream>>>(
        nullptr, nullptr, p3, 64, 64, accum, 3, nullptr);

    double c0 = (double)NC * 512.0 * 512.0;
    double c1 = (double)NC * 256.0 * 256.0;
    double c2 = (double)NC * 128.0 * 128.0;
    double c3 = (double)NC * 64.0 * 64.0;
    finalize_kernel<<<1, 1, 0, stream>>>(accum, out, c0, c1, c2, c3);
}

// Round 2
// 327.432 us; speedup vs baseline: 1.8375x; 1.8375x over previous
//
#include <hip/hip_runtime.h>

typedef float f2 __attribute__((ext_vector_type(2)));

#define PAD 5
#define WSZ 11

// Precomputed normalized 11-tap Gaussian (sigma=1.5) — matches fp32 ref far
// within the 1.4e-2 threshold. Hard-coded to keep weights out of VGPRs.
__device__ __forceinline__ float gw(int k) {
    const float G[WSZ] = {
        0.0010283782f, 0.0075987580f, 0.0360007600f, 0.1093607000f,
        0.2130055600f, 0.2660117400f,
        0.2130055600f, 0.1093607000f, 0.0360007600f, 0.0075987580f, 0.0010283782f };
    return G[k];
}

__global__ __launch_bounds__(64) void init_accum_kernel(double* accum) {
    if (threadIdx.x < 4) accum[threadIdx.x] = 0.0;
}

// 4 independent waves per 256-thread block; each wave owns a 64-col x RT-row
// strip and a private 80-entry LDS row (no cross-wave sharing -> no barriers;
// same-wave DS ordering + wavefront fences keep prefetch loads in flight).
// Depth-2 global prefetch into register slots P0/P1 (slot = it&1, static after
// unroll-by-12). Horizontal 11-tap via the 74-wide LDS row; vertical 11-tap
// via a 12-deep register ring (static indices). 2x2 pool fused.
//
// __launch_bounds__(256, 4): 128-VGPR cap. (256,6)'s 85-VGPR cap made the
// allocator spill the 60-float vertical ring to scratch (VGPR 60->40,
// FETCH 107->762 MB, 2.2x slower). With actual usage ~60 <= 64 the HW still
// reaches 8 waves/SIMD; occupancy stays grid-limited at 24 waves/CU.
template<int RT, bool PLANAR>
__global__ __launch_bounds__(256, 4) void ssim_scale_kernel(
    const float* __restrict__ img1, const float* __restrict__ img2,
    const f2* __restrict__ pair,
    int H, int W,
    double* __restrict__ accum, int slot,
    f2* __restrict__ pout)
{
    __shared__ f2 st_all[4][80];          // per-wave strip: cols ox-5 .. ox+68
    const int lane = threadIdx.x & 63;
    const int wv   = threadIdx.x >> 6;
    f2* st = st_all[wv];
    const int ox = blockIdx.x * 64;
    const int r0 = (blockIdx.y * 4 + wv) * RT;
    const int z  = blockIdx.z;
    const size_t base = (size_t)z * H * W;

    constexpr int NIT = RT + 10;
    const float C1 = 1e-4f, C2 = 9e-4f;

    // Per-lane column geometry (iteration-invariant).
    const int c0 = ox - PAD + lane;
    const bool m0 = (c0 >= 0) & (c0 < W);
    const int c0c = min(max(c0, 0), W - 1);
    const int c1 = ox + 59 + lane;                 // halo cols, lanes 0..9
    const bool m1 = (lane < 10) & (c1 < W);
    const int c1c = min(c1, W - 1);

    f2 P0a = {0.f, 0.f}, P0b = {0.f, 0.f};
    f2 P1a = {0.f, 0.f}, P1b = {0.f, 0.f};

    auto issue = [&](int y, f2& A, f2& B) {
        int yc = min(max(y, 0), H - 1);            // clamp; mask at consume
        const size_t roff = base + (size_t)yc * W; // wave-uniform -> SALU
        if (PLANAR) {
            A = (f2){ img1[roff + c0c], img2[roff + c0c] };
            if (lane < 10) B = (f2){ img1[roff + c1c], img2[roff + c1c] };
        } else {
            A = pair[roff + c0c];
            if (lane < 10) B = pair[roff + c1c];
        }
    };

    issue(r0 - PAD + 0, P0a, P0b);
    issue(r0 - PAD + 1, P1a, P1b);

    f2 rmu[12], rsq[12];
    float rxx[12];
    f2 psum = {0.f, 0.f};
    float local = 0.f;
    const f2 zero = {0.f, 0.f};

#pragma clang loop unroll(disable)
    for (int b0 = 0; b0 < NIT; b0 += 12) {
#pragma unroll
        for (int j = 0; j < 12; ++j) {
            const int it = b0 + j;
            if (it < NIT) {
                const int y = r0 - PAD + it;
                const bool yok = (y >= 0) & (y < H);   // wave-uniform

                f2& ca = (j & 1) ? P1a : P0a;          // static slot select
                f2& cb = (j & 1) ? P1b : P0b;
                f2 wa = (yok & m0) ? ca : zero;        // vmcnt wait lands here
                f2 wb = (yok & m1) ? cb : zero;
                issue(y + 2, ca, cb);                  // refill slot: depth-2 prefetch

                __builtin_amdgcn_fence(__ATOMIC_ACQ_REL, "wavefront");
                __builtin_amdgcn_wave_barrier();
                st[lane] = wa;
                if (lane < 10) st[64 + lane] = wb;
                __builtin_amdgcn_fence(__ATOMIC_ACQ_REL, "wavefront");
                __builtin_amdgcn_wave_barrier();

                // Horizontal 11-tap (same-wave DS ordering guarantees RAW).
                f2 hmu = zero, hsq = zero;
                float hxx = 0.f;
#pragma unroll
                for (int k = 0; k < WSZ; ++k) {
                    f2 p = st[lane + k];
                    hmu += p * gw(k);
                    hsq += (p * p) * gw(k);
                    hxx += (p.x * p.y) * gw(k);
                }
                rmu[it % 12] = hmu;                    // it%12 == j: static
                rsq[it % 12] = hsq;
                rxx[it % 12] = hxx;

                // Fused 2x2 avg-pool from the staged raw row.
                if (pout != nullptr) {
                    const int yt = it - PAD;
                    if ((yt >= 0) & (yt < RT) & (lane < 32)) {
                        f2 s01 = st[PAD + 2 * lane] + st[PAD + 2 * lane + 1];
                        if ((yt & 1) == 0) {
                            psum = s01;
                        } else {
                            f2 m = (psum + s01) * 0.25f;
                            const int Wo = W >> 1;
                            pout[(size_t)z * (H >> 1) * Wo +
                                 (size_t)((r0 + yt) >> 1) * Wo + (ox >> 1) + lane] = m;
                        }
                    }
                }

                // Vertical 11-tap + SSIM.
                if (it >= 10) {
                    f2 vmu = zero, vsq = zero;
                    float vxx = 0.f;
#pragma unroll
                    for (int k = 0; k < WSZ; ++k) {
                        const int s = (j + 2 + k) % 12;  // static after unroll
                        vmu += rmu[s] * gw(k);
                        vsq += rsq[s] * gw(k);
                        vxx += rxx[s] * gw(k);
                    }
                    const float mu1 = vmu.x, mu2 = vmu.y;
                    const float mu11 = mu1 * mu1, mu22 = mu2 * mu2, mu12 = mu1 * mu2;
                    const float sig1 = vsq.x - mu11;
                    const float sig2 = vsq.y - mu22;
                    const float sig12 = vxx - mu12;
                    const float num = (2.f * mu12 + C1) * (2.f * sig12 + C2);
                    const float den = (mu11 + mu22 + C1) * (sig1 + sig2 + C2);
                    local += num * __builtin_amdgcn_rcpf(den);
                }
            }
        }
    }

#pragma unroll
    for (int off = 32; off > 0; off >>= 1) local += __shfl_down(local, off);
    if (lane == 0) atomicAdd(&accum[slot], (double)local);
}

__global__ void finalize_kernel(const double* __restrict__ accum, float* __restrict__ out,
                                double c0, double c1, double c2, double c3)
{
    const double w[4] = {0.0448, 0.2856, 0.3001, 0.2363};
    const double cnt[4] = {c0, c1, c2, c3};
    double loss = 0.0;
#pragma unroll
    for (int s = 0; s < 4; ++s) loss += w[s] * (1.0 - accum[s] / cnt[s]);
    out[0] = (float)loss;
}

extern "C" void kernel_launch(void* const* d_in, const int* in_sizes, int n_in,
                              void* d_out, int out_size, void* d_ws, size_t ws_size,
                              hipStream_t stream) {
    const float* img1 = (const float*)d_in[0];
    const float* img2 = (const float*)d_in[1];
    float* out = (float*)d_out;

    const int H0 = 512, W0 = 512;
    const int NC = in_sizes[0] / (H0 * W0);  // 48

    double* accum = (double*)d_ws;
    f2* p1 = (f2*)((char*)d_ws + 64);                 // NC*256*256
    f2* p2 = p1 + (size_t)NC * 256 * 256;             // NC*128*128
    f2* p3 = p2 + (size_t)NC * 128 * 128;             // NC*64*64

    init_accum_kernel<<<1, 64, 0, stream>>>(accum);

    // Scale 0: RT=32, 16 strips, 4 waves/block -> 8x4x48 blocks = 6144 waves
    //          (24 waves/CU nominal vs 12 before; halo VALU +13.5%)
    ssim_scale_kernel<32, true><<<dim3(8, 4, NC), 256, 0, stream>>>(
        img1, img2, nullptr, 512, 512, accum, 0, p1);
    // Scale 1: RT=8, 32 strips -> 4x8x48 blocks = 6144 waves (was 3072)
    ssim_scale_kernel<8, false><<<dim3(4, 8, NC), 256, 0, stream>>>(
        nullptr, nullptr, p1, 256, 256, accum, 1, p2);
    // Scale 2: RT=8, 16 strips -> 2x4x48 blocks = 1536 waves
    ssim_scale_kernel<8, false><<<dim3(2, 4, NC), 256, 0, stream>>>(
        nullptr, nullptr, p2, 128, 128, accum, 2, p3);
    // Scale 3: RT=8, 8 strips -> 1x2x48 blocks = 384 waves
    ssim_scale_kernel<8, false><<<dim3(1, 2, NC), 256, 0, stream>>>(
        nullptr, nullptr, p3, 64, 64, accum, 3, nullptr);

    double c0 = (double)NC * 512.0 * 512.0;
    double c1 = (double)NC * 256.0 * 256.0;
    double c2 = (double)NC * 128.0 * 128.0;
    double c3 = (double)NC * 64.0 * 64.0;
    finalize_kernel<<<1, 1, 0, stream>>>(accum, out, c0, c1, c2, c3);
}

// Round 3
// 246.028 us; speedup vs baseline: 2.4455x; 1.3309x over previous
//
#include <hip/hip_runtime.h>

typedef float f2 __attribute__((ext_vector_type(2)));
typedef float f4 __attribute__((ext_vector_type(4)));

#define PAD 5
#define WSZ 11

// Precomputed normalized 11-tap Gaussian (sigma=1.5) — matches fp32 ref far
// within the 1.4e-2 threshold. Hard-coded to keep weights out of VGPRs.
__device__ __forceinline__ float gw(int k) {
    const float G[WSZ] = {
        0.0010283782f, 0.0075987580f, 0.0360007600f, 0.1093607000f,
        0.2130055600f, 0.2660117400f,
        0.2130055600f, 0.1093607000f, 0.0360007600f, 0.0075987580f, 0.0010283782f };
    return G[k];
}

__global__ __launch_bounds__(64) void init_accum_kernel(double* accum) {
    if (threadIdx.x < 4) accum[threadIdx.x] = 0.0;
}

// Pyramid pre-pass: builds all three pooled levels (2x2, 4x4, 8x8 avg chains,
// identical to iterated avg_pool2) directly from the planar inputs, stored as
// interleaved f2 pairs. Fully lane-local (lane i owns input cols 8i..8i+7 ->
// p1 cols 4i.., p2 cols 2i.., p3 col i), zero shuffles, zero LDS, all loads
// and stores coalesced vector ops. This decouples the 4 SSIM scales so they
// can run concurrently in ONE dispatch.
__global__ __launch_bounds__(64) void pyramid_kernel(
    const float* __restrict__ img1, const float* __restrict__ img2,
    f2* __restrict__ p1, f2* __restrict__ p2, f2* __restrict__ p3)
{
    const int lane = threadIdx.x;        // 0..63, owns 8 input cols
    const int rb   = blockIdx.x;         // 0..63, owns 8 input rows
    const int z    = blockIdx.y;

    const float* i1 = img1 + (size_t)z * 262144 + (size_t)rb * 8 * 512 + lane * 8;
    const float* i2 = img2 + (size_t)z * 262144 + (size_t)rb * 8 * 512 + lane * 8;
    f2* q1 = p1 + (size_t)z * 65536 + (size_t)(rb * 4) * 256 + lane * 4;
    f2* q2 = p2 + (size_t)z * 16384 + (size_t)(rb * 2) * 128 + lane * 2;
    f2* q3 = p3 + (size_t)z * 4096  + (size_t)rb * 64 + lane;

    f2 acc2a = {0.f, 0.f}, acc2b = {0.f, 0.f}, acc3 = {0.f, 0.f};
#pragma unroll
    for (int rr = 0; rr < 4; ++rr) {
        f4 a0 = *(const f4*)(i1 + (2 * rr) * 512);
        f4 a1 = *(const f4*)(i1 + (2 * rr) * 512 + 4);
        f4 a2 = *(const f4*)(i1 + (2 * rr + 1) * 512);
        f4 a3 = *(const f4*)(i1 + (2 * rr + 1) * 512 + 4);
        f4 b0 = *(const f4*)(i2 + (2 * rr) * 512);
        f4 b1 = *(const f4*)(i2 + (2 * rr) * 512 + 4);
        f4 b2 = *(const f4*)(i2 + (2 * rr + 1) * 512);
        f4 b3 = *(const f4*)(i2 + (2 * rr + 1) * 512 + 4);
        f2 v0 = { (a0.x + a0.y + a2.x + a2.y) * 0.25f, (b0.x + b0.y + b2.x + b2.y) * 0.25f };
        f2 v1 = { (a0.z + a0.w + a2.z + a2.w) * 0.25f, (b0.z + b0.w + b2.z + b2.w) * 0.25f };
        f2 v2 = { (a1.x + a1.y + a3.x + a3.y) * 0.25f, (b1.x + b1.y + b3.x + b3.y) * 0.25f };
        f2 v3 = { (a1.z + a1.w + a3.z + a3.w) * 0.25f, (b1.z + b1.w + b3.z + b3.w) * 0.25f };
        *(f4*)(q1 + rr * 256)     = (f4){ v0.x, v0.y, v1.x, v1.y };
        *(f4*)(q1 + rr * 256 + 2) = (f4){ v2.x, v2.y, v3.x, v3.y };
        acc2a += v0 + v1;
        acc2b += v2 + v3;
        if (rr & 1) {
            f2 u0 = acc2a * 0.25f, u1 = acc2b * 0.25f;
            *(f4*)(q2 + (rr >> 1) * 128) = (f4){ u0.x, u0.y, u1.x, u1.y };
            acc3 += u0 + u1;
            acc2a = (f2){0.f, 0.f};
            acc2b = (f2){0.f, 0.f};
        }
    }
    *q3 = acc3 * 0.25f;
}

// Per-wave SSIM strip body: 64-col x RT-row strip. Depth-2 global prefetch
// into register slots P0/P1 (slot = it&1, static after unroll-by-12).
// Horizontal 11-tap via a 74-wide private LDS row (same-wave DS ordering;
// wavefront fences pin the compiler, emit no waitcnt -> prefetch loads stay
// in flight). Vertical 11-tap via a 12-deep register ring (static indices).
template<int RT, bool PLANAR>
__device__ __forceinline__ void ssim_body(
    const float* __restrict__ img1, const float* __restrict__ img2,
    const f2* __restrict__ pair,
    int H, int W, int bx, int sy, int z,
    double* __restrict__ accum, int slot, f2* st, int lane)
{
    const int ox = bx * 64;
    const int r0 = sy * RT;
    const size_t base = (size_t)z * H * W;

    constexpr int NIT = RT + 10;
    const float C1 = 1e-4f, C2 = 9e-4f;

    // Per-lane column geometry (iteration-invariant).
    const int c0 = ox - PAD + lane;
    const bool m0 = (c0 >= 0) & (c0 < W);
    const int c0c = min(max(c0, 0), W - 1);
    const int c1 = ox + 59 + lane;                 // halo cols, lanes 0..9
    const bool m1 = (lane < 10) & (c1 < W);
    const int c1c = min(c1, W - 1);

    f2 P0a = {0.f, 0.f}, P0b = {0.f, 0.f};
    f2 P1a = {0.f, 0.f}, P1b = {0.f, 0.f};

    auto issue = [&](int y, f2& A, f2& B) {
        int yc = min(max(y, 0), H - 1);            // clamp; mask at consume
        const size_t roff = base + (size_t)yc * W; // wave-uniform -> SALU
        if (PLANAR) {
            A = (f2){ img1[roff + c0c], img2[roff + c0c] };
            if (lane < 10) B = (f2){ img1[roff + c1c], img2[roff + c1c] };
        } else {
            A = pair[roff + c0c];
            if (lane < 10) B = pair[roff + c1c];
        }
    };

    issue(r0 - PAD + 0, P0a, P0b);
    issue(r0 - PAD + 1, P1a, P1b);

    f2 rmu[12], rsq[12];
    float rxx[12];
    float local = 0.f;
    const f2 zero = {0.f, 0.f};

#pragma clang loop unroll(disable)
    for (int b0 = 0; b0 < NIT; b0 += 12) {
#pragma unroll
        for (int j = 0; j < 12; ++j) {
            const int it = b0 + j;
            if (it < NIT) {
                const int y = r0 - PAD + it;
                const bool yok = (y >= 0) & (y < H);   // wave-uniform

                f2& ca = (j & 1) ? P1a : P0a;          // static slot select
                f2& cb = (j & 1) ? P1b : P0b;
                f2 wa = (yok & m0) ? ca : zero;        // vmcnt wait lands here
                f2 wb = (yok & m1) ? cb : zero;
                issue(y + 2, ca, cb);                  // refill slot: depth-2 prefetch

                __builtin_amdgcn_fence(__ATOMIC_ACQ_REL, "wavefront");
                __builtin_amdgcn_wave_barrier();
                st[lane] = wa;
                if (lane < 10) st[64 + lane] = wb;
                __builtin_amdgcn_fence(__ATOMIC_ACQ_REL, "wavefront");
                __builtin_amdgcn_wave_barrier();

                // Horizontal 11-tap (same-wave DS ordering guarantees RAW).
                f2 hmu = zero, hsq = zero;
                float hxx = 0.f;
#pragma unroll
                for (int k = 0; k < WSZ; ++k) {
                    f2 p = st[lane + k];
                    hmu += p * gw(k);
                    hsq += (p * p) * gw(k);
                    hxx += (p.x * p.y) * gw(k);
                }
                rmu[it % 12] = hmu;                    // it%12 == j: static
                rsq[it % 12] = hsq;
                rxx[it % 12] = hxx;

                // Vertical 11-tap + SSIM.
                if (it >= 10) {
                    f2 vmu = zero, vsq = zero;
                    float vxx = 0.f;
#pragma unroll
                    for (int k = 0; k < WSZ; ++k) {
                        const int s = (j + 2 + k) % 12;  // static after unroll
                        vmu += rmu[s] * gw(k);
                        vsq += rsq[s] * gw(k);
                        vxx += rxx[s] * gw(k);
                    }
                    const float mu1 = vmu.x, mu2 = vmu.y;
                    const float mu11 = mu1 * mu1, mu22 = mu2 * mu2, mu12 = mu1 * mu2;
                    const float sig1 = vsq.x - mu11;
                    const float sig2 = vsq.y - mu22;
                    const float sig12 = vxx - mu12;
                    const float num = (2.f * mu12 + C1) * (2.f * sig12 + C2);
                    const float den = (mu11 + mu22 + C1) * (sig1 + sig2 + C2);
                    local += num * __builtin_amdgcn_rcpf(den);
                }
            }
        }
    }

#pragma unroll
    for (int off = 32; off > 0; off >>= 1) local += __shfl_down(local, off);
    if (lane == 0) atomicAdd(&accum[slot], (double)local);
}

// All 4 scales in ONE dispatch. 128-thread blocks = 2 independent waves on
// adjacent row strips of the same (scale, bx, z). Scales interleaved through
// the block-index space in groups of 29 (16:8:4:1 ratio matches per-channel
// block counts 32:16:8:2) so every scale is co-resident from t=0; the small
// scales execute inside scale-0's shadow and the 3 kernel-boundary drains of
// the sequential version disappear.
// __launch_bounds__(128,4): 128-VGPR cap — far above the ~60 used (the
// (256,6)/85-cap variant spilled the vertical ring to scratch: 2.2x slower).
__global__ __launch_bounds__(128, 4) void ssim_fused_kernel(
    const float* __restrict__ img1, const float* __restrict__ img2,
    const f2* __restrict__ p1, const f2* __restrict__ p2, const f2* __restrict__ p3,
    double* __restrict__ accum)
{
    __shared__ f2 st_all[2][80];
    const int lane = threadIdx.x & 63;
    const int wv   = threadIdx.x >> 6;
    f2* st = st_all[wv];

    const int i = blockIdx.x;
    const int g = i / 29;                  // magic-mul div
    const int r = i - g * 29;

    if (r < 16) {                          // scale 0: RT=64, 512x512, planar
        const int l = g * 16 + r;
        const int bx = l & 7, by = (l >> 3) & 3, z = l >> 5;
        ssim_body<64, true>(img1, img2, nullptr, 512, 512,
                            bx, by * 2 + wv, z, accum, 0, st, lane);
    } else if (r < 24) {                   // scale 1: RT=32, 256x256
        const int l = g * 8 + (r - 16);
        const int bx = l & 3, by = (l >> 2) & 3, z = l >> 4;
        ssim_body<32, false>(nullptr, nullptr, p1, 256, 256,
                             bx, by * 2 + wv, z, accum, 1, st, lane);
    } else if (r < 28) {                   // scale 2: RT=16, 128x128
        const int l = g * 4 + (r - 24);
        const int bx = l & 1, by = (l >> 1) & 3, z = l >> 3;
        ssim_body<16, false>(nullptr, nullptr, p2, 128, 128,
                             bx, by * 2 + wv, z, accum, 2, st, lane);
    } else {                               // scale 3: RT=16, 64x64
        const int l = g;
        const int by = l & 1, z = l >> 1;
        ssim_body<16, false>(nullptr, nullptr, p3, 64, 64,
                             0, by * 2 + wv, z, accum, 3, st, lane);
    }
}

__global__ void finalize_kernel(const double* __restrict__ accum, float* __restrict__ out,
                                double c0, double c1, double c2, double c3)
{
    const double w[4] = {0.0448, 0.2856, 0.3001, 0.2363};
    const double cnt[4] = {c0, c1, c2, c3};
    double loss = 0.0;
#pragma unroll
    for (int s = 0; s < 4; ++s) loss += w[s] * (1.0 - accum[s] / cnt[s]);
    out[0] = (float)loss;
}

extern "C" void kernel_launch(void* const* d_in, const int* in_sizes, int n_in,
                              void* d_out, int out_size, void* d_ws, size_t ws_size,
                              hipStream_t stream) {
    const float* img1 = (const float*)d_in[0];
    const float* img2 = (const float*)d_in[1];
    float* out = (float*)d_out;

    const int H0 = 512, W0 = 512;
    const int NC = in_sizes[0] / (H0 * W0);  // 48

    double* accum = (double*)d_ws;
    f2* p1 = (f2*)((char*)d_ws + 64);                 // NC*256*256
    f2* p2 = p1 + (size_t)NC * 256 * 256;             // NC*128*128
    f2* p3 = p2 + (size_t)NC * 128 * 128;             // NC*64*64

    init_accum_kernel<<<1, 64, 0, stream>>>(accum);

    // Pyramid: 64 row-blocks x NC channels, 1 wave each (~134 MB traffic).
    pyramid_kernel<<<dim3(64, NC), 64, 0, stream>>>(img1, img2, p1, p2, p3);

    // Fused SSIM: per channel 32+16+8+2 = 58 blocks = 2 groups of 29.
    const int NBLK = NC * 58;
    ssim_fused_kernel<<<dim3(NBLK), 128, 0, stream>>>(img1, img2, p1, p2, p3, accum);

    double c0 = (double)NC * 512.0 * 512.0;
    double c1 = (double)NC * 256.0 * 256.0;
    double c2 = (double)NC * 128.0 * 128.0;
    double c3 = (double)NC * 64.0 * 64.0;
    finalize_kernel<<<1, 1, 0, stream>>>(accum, out, c0, c1, c2, c3);
}